// Round 6
// baseline (190.232 us; speedup 1.0000x reference)
//
#include <hip/hip_runtime.h>

#define VQ_K 512
#define VQ_D 64
#define VQ_N (32 * 64 * 64)   // B*H*W = 131072
#define CH_STRIDE 4096        // H*W
#define B_STRIDE  262144      // C*H*W
#define KSPLIT 4
#define KPW (VQ_K / KSPLIT)   // 128 codes per wave
#define KB 8                  // codes per register block

// Pre-pass: squared norms of codebook rows into workspace.
__global__ void cb_sqr_kernel(const float* __restrict__ cb,
                              float* __restrict__ cbsq) {
    int k = blockIdx.x * blockDim.x + threadIdx.x;
    if (k < VQ_K) {
        float s = 0.f;
        #pragma unroll
        for (int d = 0; d < VQ_D; ++d) {
            float v = cb[k * VQ_D + d];
            s = fmaf(v, v, s);
        }
        cbsq[k] = s;
    }
}

// R3-R5 post-mortem: the RA will NOT keep a 64-float x-vector per lane
// (VGPR stuck at 44; ~4.3GB/launch of per-code x reloads through L2/L3 = the
// 128us). Structural fix instead of an RA fight:
//   - x tile staged in LDS as sx[dim][pos]: reads are 2-way bank-aliased
//     (free) and use ONE base reg + imm offsets (no per-load address VALU,
//     which strided global reloads required).
//   - k-loop blocked 8 codes x 8-dim chunks: only 8 x-values live at a time
//     (RA-friendly), x re-read per code drops 64->8 LDS reads (~537MB total,
//     hidden under VALU).
__global__ __launch_bounds__(256) void vq_argmin_kernel(
        const float* __restrict__ x,
        const float* __restrict__ cb,
        const float* __restrict__ cbsq,
        int* __restrict__ out) {
    __shared__ float sx[VQ_D][64];        // [dim][pos], 16 KB
    __shared__ float sbest[KSPLIT][64];   // 1 KB
    __shared__ int   sbi[KSPLIT][64];     // 1 KB

    int t   = threadIdx.x;
    int pos = t & 63;                                   // position in block
    int w   = __builtin_amdgcn_readfirstlane(t >> 6);   // wave id, uniform
    int n0  = blockIdx.x * 64;
    int b   = n0 >> 12;       // batch (64 | 4096: whole block same batch)
    int p0  = n0 & 4095;      // first position in this block

    // Stage x tile: wave w loads dim-rows {w, w+4, ..., w+60}; each row read
    // is 64 consecutive floats (fully coalesced), written at 2-way bank alias.
    const float* xrow = x + b * B_STRIDE + p0;
    #pragma unroll
    for (int r = 0; r < 16; ++r) {
        int d = w + r * 4;
        sx[d][pos] = xrow[d * CH_STRIDE + pos];
    }
    __syncthreads();

    // ||x||^2 in fp32, 4 accumulators, same dim->acc mapping as R1-R5
    // (a_i gets dims == i mod 4, ascending) -> absmax 0.0 so far.
    float s0 = 0.f, s1 = 0.f, s2 = 0.f, s3 = 0.f;
    #pragma unroll
    for (int d = 0; d < VQ_D; d += 4) {
        float v0 = sx[d + 0][pos], v1 = sx[d + 1][pos];
        float v2 = sx[d + 2][pos], v3 = sx[d + 3][pos];
        s0 = fmaf(v0, v0, s0);
        s1 = fmaf(v1, v1, s1);
        s2 = fmaf(v2, v2, s2);
        s3 = fmaf(v3, v3, s3);
    }
    float insq = (s0 + s1) + (s2 + s3);

    float best = 3.4e38f;
    int bi = 0;
    const float* rowbase = cb + w * (KPW * VQ_D);   // uniform -> scalar loads
    const float* sqbase  = cbsq + w * KPW;

    #pragma unroll 1   // keep rolled: body stays I$-resident, no cross-kb hoist
    for (int kb = 0; kb < KPW; kb += KB) {
        float a0[KB], a1[KB], a2[KB], a3[KB];
        #pragma unroll
        for (int j = 0; j < KB; ++j) { a0[j] = 0.f; a1[j] = 0.f; a2[j] = 0.f; a3[j] = 0.f; }

        #pragma unroll
        for (int c = 0; c < 8; ++c) {
            // 8 x-values for this dim chunk: one ds_read_b32 each, imm offset,
            // 2-way bank alias (free), only 8 live registers.
            float xv0 = sx[c * 8 + 0][pos], xv1 = sx[c * 8 + 1][pos];
            float xv2 = sx[c * 8 + 2][pos], xv3 = sx[c * 8 + 3][pos];
            float xv4 = sx[c * 8 + 4][pos], xv5 = sx[c * 8 + 5][pos];
            float xv6 = sx[c * 8 + 6][pos], xv7 = sx[c * 8 + 7][pos];
            #pragma unroll
            for (int j = 0; j < KB; ++j) {
                const float* row = rowbase + (kb + j) * VQ_D + c * 8; // uniform
                a0[j] = fmaf(xv0, row[0], a0[j]);
                a1[j] = fmaf(xv1, row[1], a1[j]);
                a2[j] = fmaf(xv2, row[2], a2[j]);
                a3[j] = fmaf(xv3, row[3], a3[j]);
                a0[j] = fmaf(xv4, row[4], a0[j]);
                a1[j] = fmaf(xv5, row[5], a1[j]);
                a2[j] = fmaf(xv6, row[6], a2[j]);
                a3[j] = fmaf(xv7, row[7], a3[j]);
            }
        }

        #pragma unroll
        for (int j = 0; j < KB; ++j) {
            float dot  = (a0[j] + a1[j]) + (a2[j] + a3[j]);
            float dist = (insq + sqbase[kb + j]) - 2.f * dot;
            if (dist < best) { best = dist; bi = w * KPW + kb + j; }  // strict <
        }
    }

    // Cross-wave argmin reduce via LDS, ascending k-group order with
    // strict < preserves np.argmin first-occurrence tie-breaking.
    sbest[w][pos] = best;
    sbi[w][pos]   = bi;
    __syncthreads();
    if (t < 64) {
        float bb = sbest[0][t];
        int   ii = sbi[0][t];
        #pragma unroll
        for (int j = 1; j < KSPLIT; ++j) {
            float c = sbest[j][t];
            if (c < bb) { bb = c; ii = sbi[j][t]; }
        }
        out[n0 + t] = ii;
    }
}

extern "C" void kernel_launch(void* const* d_in, const int* in_sizes, int n_in,
                              void* d_out, int out_size, void* d_ws, size_t ws_size,
                              hipStream_t stream) {
    const float* x  = (const float*)d_in[0];   // [32,64,64,64] fp32
    const float* cb = (const float*)d_in[1];   // [512,64] fp32
    int* out = (int*)d_out;                    // [32,64,64] int32
    float* cbsq = (float*)d_ws;                // 512 floats scratch

    cb_sqr_kernel<<<1, VQ_K, 0, stream>>>(cb, cbsq);
    vq_argmin_kernel<<<VQ_N / 64, 256, 0, stream>>>(x, cb, cbsq, out);
}

// Round 7
// 187.493 us; speedup vs baseline: 1.0146x; 1.0146x over previous
//
#include <hip/hip_runtime.h>

#define VQ_K 512
#define VQ_D 64
#define VQ_N (32 * 64 * 64)   // B*H*W = 131072
#define CH_STRIDE 4096        // H*W
#define B_STRIDE  262144      // C*H*W
#define KSPLIT 4
#define KPW (VQ_K / KSPLIT)   // 128 codes per wave
#define KB 8                  // codes per register block

typedef float f32x4 __attribute__((ext_vector_type(4)));

// Pre-pass: squared norms of codebook rows. R6 post-mortem: <<<1,512>>> ran
// 8 waves on ONE CU, latency-bound (~30-40us of the ~52us JSON-vs-dispatch
// gap). 8 blocks x 64 threads + float4 loads; fmaf chain kept in ascending-d
// order so cbsq bits are identical to all prior passing rounds.
__global__ void cb_sqr_kernel(const float* __restrict__ cb,
                              float* __restrict__ cbsq) {
    int k = blockIdx.x * 64 + threadIdx.x;   // grid 8x64 = 512 exactly
    const f32x4* row = (const f32x4*)(cb + k * VQ_D);
    float s = 0.f;
    #pragma unroll
    for (int c = 0; c < 16; ++c) {
        f32x4 v = row[c];
        s = fmaf(v.x, v.x, s);
        s = fmaf(v.y, v.y, s);
        s = fmaf(v.z, v.z, s);
        s = fmaf(v.w, v.w, s);
    }
    cbsq[k] = s;
}

// R6 post-mortem (per-CU accounting at 637 cyc/kb-unit wall): LDS pipe was
// the most-loaded resource — 64 ds_read_b32/kb-unit x 5.8cyc = 371 cyc (58%)
// vs VALU 292 (46%). Fix: x tile as [pos][dim] with the G4 XOR swizzle
// (float4-granule: idx4 ^= pos&7), read via ds_read_b128 -> 16 LDS insts per
// kb-unit (192 cyc, 30%) instead of 64. Everything arithmetic is bit-identical
// to R1-R6 (same dim->acc mapping, dot/dist association, ascending-k strict <).
__global__ __launch_bounds__(256) void vq_argmin_kernel(
        const float* __restrict__ x,
        const float* __restrict__ cb,
        const float* __restrict__ cbsq,
        int* __restrict__ out) {
    __shared__ float sx[VQ_D * 64];       // [pos][dim] swizzled, 16 KB
    __shared__ float sbest[KSPLIT][64];   // 1 KB
    __shared__ int   sbi[KSPLIT][64];     // 1 KB

    int t   = threadIdx.x;
    int pos = t & 63;                                   // position in block
    int w   = __builtin_amdgcn_readfirstlane(t >> 6);   // wave id, uniform
    int n0  = blockIdx.x * 64;
    int b   = n0 >> 12;       // batch (64 | 4096: whole block same batch)
    int p0  = n0 & 4095;      // first position in this block

    // Stage x tile. Global side unchanged (coalesced along pos for fixed d).
    // LDS side: element (pos,d) lives at float-index pos*64 + (d ^ ((pos&7)<<2))
    // == byte addr pos*256 + (4d ^ ((pos&7)<<4)) — the G4 swizzle, preserving
    // 16B alignment of 4-dim groups.
    const float* xrow = x + b * B_STRIDE + p0;
    int px4 = (pos & 7) << 2;
    #pragma unroll
    for (int r = 0; r < 16; ++r) {
        int d = w + r * 4;
        sx[pos * 64 + (d ^ px4)] = xrow[d * CH_STRIDE + pos];
    }
    __syncthreads();

    const f32x4* sxv = (const f32x4*)sx;
    int pb = pos * 16;        // float4-granule base of this lane's row
    int px = pos & 7;         // XOR key at float4 granule

    // ||x||^2 in fp32, 4 accumulators, dims ascending — bit-identical
    // association to R1-R6 (absmax 0.0 every round).
    float s0 = 0.f, s1 = 0.f, s2 = 0.f, s3 = 0.f;
    #pragma unroll
    for (int c = 0; c < 8; ++c) {
        f32x4 xa = sxv[pb + ((c * 2 + 0) ^ px)];   // dims c*8 .. c*8+3
        f32x4 xb = sxv[pb + ((c * 2 + 1) ^ px)];   // dims c*8+4 .. c*8+7
        s0 = fmaf(xa.x, xa.x, s0);
        s1 = fmaf(xa.y, xa.y, s1);
        s2 = fmaf(xa.z, xa.z, s2);
        s3 = fmaf(xa.w, xa.w, s3);
        s0 = fmaf(xb.x, xb.x, s0);
        s1 = fmaf(xb.y, xb.y, s1);
        s2 = fmaf(xb.z, xb.z, s2);
        s3 = fmaf(xb.w, xb.w, s3);
    }
    float insq = (s0 + s1) + (s2 + s3);

    float best = 3.4e38f;
    int bi = 0;
    const float* rowbase = cb + w * (KPW * VQ_D);   // uniform -> scalar loads
    const float* sqbase  = cbsq + w * KPW;

    #pragma unroll 1   // keep rolled: I$-resident body, no cross-kb hoist
    for (int kb = 0; kb < KPW; kb += KB) {
        float a0[KB], a1[KB], a2[KB], a3[KB];
        #pragma unroll
        for (int j = 0; j < KB; ++j) { a0[j] = 0.f; a1[j] = 0.f; a2[j] = 0.f; a3[j] = 0.f; }

        #pragma unroll
        for (int c = 0; c < 8; ++c) {
            // 8 x-values for this dim chunk: TWO ds_read_b128 (was 8 b32).
            f32x4 xa = sxv[pb + ((c * 2 + 0) ^ px)];   // dims c*8 .. +3
            f32x4 xb = sxv[pb + ((c * 2 + 1) ^ px)];   // dims c*8+4 .. +7
            #pragma unroll
            for (int j = 0; j < KB; ++j) {
                const float* row = rowbase + (kb + j) * VQ_D + c * 8; // uniform
                a0[j] = fmaf(xa.x, row[0], a0[j]);
                a1[j] = fmaf(xa.y, row[1], a1[j]);
                a2[j] = fmaf(xa.z, row[2], a2[j]);
                a3[j] = fmaf(xa.w, row[3], a3[j]);
                a0[j] = fmaf(xb.x, row[4], a0[j]);
                a1[j] = fmaf(xb.y, row[5], a1[j]);
                a2[j] = fmaf(xb.z, row[6], a2[j]);
                a3[j] = fmaf(xb.w, row[7], a3[j]);
            }
        }

        #pragma unroll
        for (int j = 0; j < KB; ++j) {
            float dot  = (a0[j] + a1[j]) + (a2[j] + a3[j]);
            float dist = (insq + sqbase[kb + j]) - 2.f * dot;
            if (dist < best) { best = dist; bi = w * KPW + kb + j; }  // strict <
        }
    }

    // Cross-wave argmin reduce via LDS, ascending k-group order with
    // strict < preserves np.argmin first-occurrence tie-breaking.
    sbest[w][pos] = best;
    sbi[w][pos]   = bi;
    __syncthreads();
    if (t < 64) {
        float bb = sbest[0][t];
        int   ii = sbi[0][t];
        #pragma unroll
        for (int j = 1; j < KSPLIT; ++j) {
            float c = sbest[j][t];
            if (c < bb) { bb = c; ii = sbi[j][t]; }
        }
        out[n0 + t] = ii;
    }
}

extern "C" void kernel_launch(void* const* d_in, const int* in_sizes, int n_in,
                              void* d_out, int out_size, void* d_ws, size_t ws_size,
                              hipStream_t stream) {
    const float* x  = (const float*)d_in[0];   // [32,64,64,64] fp32
    const float* cb = (const float*)d_in[1];   // [512,64] fp32
    int* out = (int*)d_out;                    // [32,64,64] int32
    float* cbsq = (float*)d_ws;                // 512 floats scratch

    cb_sqr_kernel<<<VQ_K / 64, 64, 0, stream>>>(cb, cbsq);
    vq_argmin_kernel<<<VQ_N / 64, 256, 0, stream>>>(x, cb, cbsq, out);
}